// Round 1
// 373.647 us; speedup vs baseline: 1.8102x; 1.8102x over previous
//
#include <hip/hip_runtime.h>
#include <hip/hip_bf16.h>

// Problem constants
#define B_    512
#define HIST_ 8
#define PRED_ 24
#define CITY_ 184
#define FEAT_ 13
#define HID_  32
#define BC_   (B_*CITY_)   // 94208 = 5888 * 16
#define FLAG_OFF 7168

// ws (float) layout (written by lstm_prep):
//   [0..4095]      Wh2[row*32+k] : W_hh + a0 (x) W_out   (t>=1 path)
//   [4096..6143]   Wf [row*16+f] : W_x[:,1:14], cols 13..15 zeroed
//   [6144..6271]   bg2[row]      : b_g + a0*b_out        (t>=1)
//   [6272..6399]   a0 [row]      : W_x[:,0]              (t==0)
//   [6400..6527]   bg0[row]      : b_g                   (t==0)
//   [6528..6559]   wout[k]
//   [6560]         bout
//   [7168]         dtype flag: 0.0f = bf16 inputs, 1.0f = fp32 inputs

struct TrueT  { static constexpr bool value = true;  };
struct FalseT { static constexpr bool value = false; };

typedef _Float16 v8hf __attribute__((ext_vector_type(8)));
typedef _Float16 v4hf __attribute__((ext_vector_type(4)));
typedef _Float16 v2hf __attribute__((ext_vector_type(2)));
typedef float    v4f  __attribute__((ext_vector_type(4)));

__device__ __forceinline__ float rcp_(float x) { return __builtin_amdgcn_rcpf(x); }
__device__ __forceinline__ float sigf(float x) { return rcp_(1.0f + __expf(-x)); }
__device__ __forceinline__ float tanhf_(float x) {
    float e = __expf(2.0f * x);
    return 1.0f - 2.0f * rcp_(e + 1.0f);   // saturates correctly
}

template<bool F32>
__device__ __forceinline__ float ldin(const void* p, long i) {
    if constexpr (F32) return ((const float*)p)[i];
    else               return __bfloat162float(((const __hip_bfloat16*)p)[i]);
}
template<bool F32>
__device__ __forceinline__ void stout(void* p, long i, float v) {
    if constexpr (F32) ((float*)p)[i] = v;
    else               ((__hip_bfloat16*)p)[i] = __float2bfloat16(v);
}

// MFMA wrappers. K16 legacy builtin guarded: the K32 fallback with zero-padded
// element slots is exactly equivalent (A/B share the (lane,elem)->k labeling,
// so any consistent labeling yields the same dot product; pad elems are 0).
__device__ __forceinline__ v4f mfma_k32(v8hf a, v8hf b, v4f c) {
    return __builtin_amdgcn_mfma_f32_16x16x32_f16(a, b, c, 0, 0, 0);
}
__device__ __forceinline__ v4f mfma_k16(v4hf a, v4hf b, v4f c) {
#if __has_builtin(__builtin_amdgcn_mfma_f32_16x16x16f16)
    return __builtin_amdgcn_mfma_f32_16x16x16f16(a, b, c, 0, 0, 0);
#else
    v8hf a8; v8hf b8;
    #pragma unroll
    for (int j = 0; j < 4; ++j) { a8[j] = a[j]; b8[j] = b[j]; }
    #pragma unroll
    for (int j = 4; j < 8; ++j) { a8[j] = (_Float16)0.f; b8[j] = (_Float16)0.f; }
    return __builtin_amdgcn_mfma_f32_16x16x32_f16(a8, b8, c, 0, 0, 0);
#endif
}

// ---- dtype detector (validated in R2) ----
__global__ void detect_dtype(const unsigned short* __restrict__ feat_raw,
                             float* __restrict__ ws) {
    __shared__ int cnt;
    int tid = threadIdx.x;
    if (tid == 0) cnt = 0;
    __syncthreads();
    int insane = 0;
    for (int i = tid; i < 4096; i += 256) {
        float v = __uint_as_float(((unsigned int)feat_raw[i]) << 16);
        if (!(fabsf(v) < 1e8f)) insane++;
    }
    if (insane) atomicAdd(&cnt, insane);
    __syncthreads();
    if (tid == 0) ws[FLAG_OFF] = (cnt > 8) ? 1.0f : 0.0f;
}

template<bool F32>
__global__ void lstm_prep(const void* __restrict__ W_in,   // (32,14)
                          const void* __restrict__ b_in,   // (32)
                          const void* __restrict__ W_out,  // (1,32)
                          const void* __restrict__ b_out,  // (1)
                          const void* __restrict__ W_ih,   // (128,32)
                          const void* __restrict__ W_hh,   // (128,32)
                          const void* __restrict__ b_ih,   // (128)
                          const void* __restrict__ b_hh,   // (128)
                          float* __restrict__ ws)
{
    if (ws[FLAG_OFF] != (F32 ? 1.0f : 0.0f)) return;
    int j = threadIdx.x;           // gate row 0..127
    if (j >= 128) return;

    float wx[14];
    #pragma unroll
    for (int c = 0; c < 14; ++c) wx[c] = 0.0f;
    float bg = ldin<F32>(b_ih, j) + ldin<F32>(b_hh, j);
    #pragma unroll
    for (int m = 0; m < 32; ++m) {
        float wihm = ldin<F32>(W_ih, j*32 + m);
        #pragma unroll
        for (int c = 0; c < 14; ++c) wx[c] = fmaf(wihm, ldin<F32>(W_in, m*14 + c), wx[c]);
        bg = fmaf(wihm, ldin<F32>(b_in, m), bg);
    }
    float a0 = wx[0];
    #pragma unroll
    for (int k = 0; k < 32; ++k)
        ws[j*32 + k] = ldin<F32>(W_hh, j*32 + k) + a0 * ldin<F32>(W_out, k);
    #pragma unroll
    for (int f = 0; f < 13; ++f) ws[4096 + j*16 + f] = wx[1 + f];
    #pragma unroll
    for (int f = 13; f < 16; ++f) ws[4096 + j*16 + f] = 0.0f;  // pad (never poison)
    float bo = ldin<F32>(b_out, 0);
    ws[6144 + j] = bg + a0 * bo;
    ws[6272 + j] = a0;
    ws[6400 + j] = bg;
    if (j < 32) ws[6528 + j] = ldin<F32>(W_out, j);
    if (j == 0) ws[6560] = bo;
}

// MFMA weight-stationary LSTM: 1 wave/block, 16 seqs/wave.
// gates(128x16) = W(128x45) . [h(32); feat(13)](45x16) per timestep, done as
// 8 row-tiles of 16x16 MFMA with fp16 hi/lo split (fp32-equivalent accuracy):
//   D = Whi.xhi + Wlo.xhi + Whi.xlo  (lo.lo dropped, ~2^-22 relative)
// Lane roles: rho=lane&15 -> A-row / B-col(seq) / D-col(seq); q=lane>>4 ->
// k-block / D-row-block. D layout (m89-verified): col=lane&15, row=4q+reg.
// Each lane owns i/f/g/o for units {4q+r, 16+4q+r} of seq rho; c-state stays
// in registers; h round-trips LDS once per step to become the next B operand.
template<bool F32>
__global__ __launch_bounds__(64, 2) void lstm_main(
    const void* __restrict__ pm25,   // (512, 8, 184, 1)
    const void* __restrict__ feat,   // (512, 32, 184, 13)
    const float* __restrict__ ws,
    void* __restrict__ out)          // (512, 24, 184, 1)
{
    __shared__ __align__(16) _Float16 hhi[16][40];   // stride 40 halfs = 80B (16B-aligned b128 reads)
    __shared__ __align__(16) _Float16 hlo[16][40];
    __shared__ __align__(16) _Float16 fbhi[16][20];  // stride 40B (8B-aligned b64 reads)
    __shared__ __align__(16) _Float16 fblo[16][20];
    if (ws[FLAG_OFF] != (F32 ? 1.0f : 0.0f)) return;

    const int lane = threadIdx.x;    // 0..63
    const int rho  = lane & 15;      // A-row / seq
    const int q    = lane >> 4;      // k-block / row-block
    const int wseq = blockIdx.x * 16;

    // ---- weights -> fp16 hi/lo A-fragments (once per wave) ----
    // A elem j of tile tt: chunk0 Wh2[16tt+rho][8q+j]; chunk1 Wf[16tt+rho][4q+j]
    v8hf Whi0[8], Wlo0[8];
    v4hf Whi1[8], Wlo1[8];
    v4f  bias2[8];
    #pragma unroll
    for (int tt = 0; tt < 8; ++tt) {
        const float* wr = ws + (16*tt + rho)*32 + 8*q;
        #pragma unroll
        for (int j = 0; j < 8; ++j) {
            const float w = wr[j];
            const _Float16 h = (_Float16)w;
            Whi0[tt][j] = h;
            Wlo0[tt][j] = (_Float16)(w - (float)h);
        }
        const float* wf = ws + 4096 + (16*tt + rho)*16 + 4*q;
        #pragma unroll
        for (int j = 0; j < 4; ++j) {
            const float w = wf[j];
            const _Float16 h = (_Float16)w;
            Whi1[tt][j] = h;
            Wlo1[tt][j] = (_Float16)(w - (float)h);
        }
        bias2[tt] = *(const v4f*)(ws + 6144 + 16*tt + 4*q);   // C rows 16tt+4q+r
    }
    float woutA[4], woutB[4];
    #pragma unroll
    for (int r = 0; r < 4; ++r) {
        woutA[r] = ws[6528 + 4*q + r];
        woutB[r] = ws[6528 + 16 + 4*q + r];
    }
    const float bo = ws[6560];

    // per-lane sequence (B/D column)
    const int seq  = wseq + rho;
    const int bb   = seq / CITY_;
    const int city = seq - bb*CITY_;
    const long out_base = (long)bb*PRED_*CITY_ + city;

    // zero feature-pad rows 13..15 once (W cols also zero, but 0*NaN poisons)
    if (q == 0) {
        #pragma unroll
        for (int c2 = 13; c2 < 16; ++c2) {
            fbhi[rho][c2] = (_Float16)0.f;
            if constexpr (F32) fblo[rho][c2] = (_Float16)0.f;
        }
    }

    // ---- feature staging metadata: 208 floats / 64 lanes, 4 slots each ----
    long faddr[4]; int fsl[4], fff[4]; bool fok[4];
    #pragma unroll
    for (int j = 0; j < 4; ++j) {
        const int e = lane + 64*j;
        fok[j] = (e < 16*FEAT_);
        const int sl = e / FEAT_;
        const int f  = e - sl*FEAT_;
        fsl[j] = sl; fff[j] = f;
        const int sq = wseq + (fok[j] ? sl : 0);
        const int b2 = sq / CITY_;
        const int c3 = sq - b2*CITY_;
        faddr[j] = ((long)(b2*(HIST_+PRED_) + HIST_)*CITY_ + c3)*FEAT_ + f;
    }
    float fval[4];
    auto ldfeat = [&]() {            // global -> regs (prefetch)
        #pragma unroll
        for (int j = 0; j < 4; ++j) {
            fval[j] = fok[j] ? ldin<F32>(feat, faddr[j]) : 0.0f;
            faddr[j] += CITY_ * FEAT_;
        }
    };
    auto wrfeat = [&]() {            // regs -> LDS (fp16 hi / lo)
        #pragma unroll
        for (int j = 0; j < 4; ++j) if (fok[j]) {
            const float v = fval[j];
            const _Float16 h = (_Float16)v;
            fbhi[fsl[j]][fff[j]] = h;
            if constexpr (F32) fblo[fsl[j]][fff[j]] = (_Float16)(v - (float)h);
        }
    };

    float cstA[4], cstB[4];          // c-state: units 4q+r / 16+4q+r, seq rho

    auto finish = [&](v4f (&acc)[8], int t, auto T0flag) {
        constexpr bool T0 = decltype(T0flag)::value;
        float hA[4], hB[4];
        #pragma unroll
        for (int r = 0; r < 4; ++r) {
            {   // unit 4q+r : i/f/g/o from tiles 0/2/4/6
                const float I = sigf(acc[0][r]);
                const float G = tanhf_(acc[4][r]);
                const float O = sigf(acc[6][r]);
                float c;
                if constexpr (T0) c = I*G;
                else              c = fmaf(sigf(acc[2][r]), cstA[r], I*G);
                cstA[r] = c;
                hA[r] = O * tanhf_(c);
            }
            {   // unit 16+4q+r : tiles 1/3/5/7
                const float I = sigf(acc[1][r]);
                const float G = tanhf_(acc[5][r]);
                const float O = sigf(acc[7][r]);
                float c;
                if constexpr (T0) c = I*G;
                else              c = fmaf(sigf(acc[3][r]), cstB[r], I*G);
                cstB[r] = c;
                hB[r] = O * tanhf_(c);
            }
        }
        // pack h -> fp16 hi/lo, stage as next step's B chunk0 (hhi[seq][unit])
        {
            v2hf p, pl;
            _Float16 h0 = (_Float16)hA[0], h1 = (_Float16)hA[1];
            p[0]=h0; p[1]=h1; *(v2hf*)&hhi[rho][4*q] = p;
            pl[0]=(_Float16)(hA[0]-(float)h0); pl[1]=(_Float16)(hA[1]-(float)h1);
            *(v2hf*)&hlo[rho][4*q] = pl;
            h0 = (_Float16)hA[2]; h1 = (_Float16)hA[3];
            p[0]=h0; p[1]=h1; *(v2hf*)&hhi[rho][4*q+2] = p;
            pl[0]=(_Float16)(hA[2]-(float)h0); pl[1]=(_Float16)(hA[3]-(float)h1);
            *(v2hf*)&hlo[rho][4*q+2] = pl;
            h0 = (_Float16)hB[0]; h1 = (_Float16)hB[1];
            p[0]=h0; p[1]=h1; *(v2hf*)&hhi[rho][16+4*q] = p;
            pl[0]=(_Float16)(hB[0]-(float)h0); pl[1]=(_Float16)(hB[1]-(float)h1);
            *(v2hf*)&hlo[rho][16+4*q] = pl;
            h0 = (_Float16)hB[2]; h1 = (_Float16)hB[3];
            p[0]=h0; p[1]=h1; *(v2hf*)&hhi[rho][16+4*q+2] = p;
            pl[0]=(_Float16)(hB[2]-(float)h0); pl[1]=(_Float16)(hB[3]-(float)h1);
            *(v2hf*)&hlo[rho][16+4*q+2] = pl;
        }
        // y_t = wout . h + bout (partial over this lane's 8 units, reduce over q)
        float y = 0.0f;
        #pragma unroll
        for (int r = 0; r < 4; ++r) {
            y = fmaf(woutA[r], hA[r], y);
            y = fmaf(woutB[r], hB[r], y);
        }
        y += __shfl_xor(y, 16);
        y += __shfl_xor(y, 32);
        if (q == 0) stout<F32>(out, out_base + (long)t*CITY_, y + bo);
    };

    // ---- t = 0 : gates = a0*x0 + bg0 (via C-init) + Wf.feat (h0 = 0) ----
    ldfeat();            // t=0 features
    wrfeat();
    ldfeat();            // t=1 features in flight
    {
        const float x0 = ldin<F32>(pm25, (long)(bb*HIST_ + (HIST_-1))*CITY_ + city);
        const v4hf fhi = *(const v4hf*)&fbhi[rho][4*q];
        v4hf flo;
        if constexpr (F32) flo = *(const v4hf*)&fblo[rho][4*q];
        v4f acc[8];
        #pragma unroll
        for (int tt = 0; tt < 8; ++tt) {
            const v4f bg0 = *(const v4f*)(ws + 6400 + 16*tt + 4*q);
            const v4f a0  = *(const v4f*)(ws + 6272 + 16*tt + 4*q);
            v4f c;
            #pragma unroll
            for (int r = 0; r < 4; ++r) c[r] = fmaf(a0[r], x0, bg0[r]);
            acc[tt] = mfma_k16(Whi1[tt], fhi, c);
            acc[tt] = mfma_k16(Wlo1[tt], fhi, acc[tt]);
            if constexpr (F32) acc[tt] = mfma_k16(Whi1[tt], flo, acc[tt]);
        }
        finish(acc, 0, TrueT{});
    }

    // ---- t = 1..23 ----
    #pragma unroll 1
    for (int t = 1; t < PRED_; ++t) {
        wrfeat();                       // features for t (loaded last iter)
        if (t < PRED_-1) ldfeat();      // prefetch t+1
        const v8hf xhi = *(const v8hf*)&hhi[rho][8*q];   // B chunk0: h units 8q..8q+7
        const v8hf xlo = *(const v8hf*)&hlo[rho][8*q];
        const v4hf fhi = *(const v4hf*)&fbhi[rho][4*q];  // B chunk1: feats 4q..4q+3
        v4hf flo;
        if constexpr (F32) flo = *(const v4hf*)&fblo[rho][4*q];
        v4f acc[8];
        #pragma unroll
        for (int tt = 0; tt < 8; ++tt) {
            acc[tt] = mfma_k32(Whi0[tt], xhi, bias2[tt]);
            acc[tt] = mfma_k32(Wlo0[tt], xhi, acc[tt]);
            acc[tt] = mfma_k32(Whi0[tt], xlo, acc[tt]);
            acc[tt] = mfma_k16(Whi1[tt], fhi, acc[tt]);
            acc[tt] = mfma_k16(Wlo1[tt], fhi, acc[tt]);
            if constexpr (F32) acc[tt] = mfma_k16(Whi1[tt], flo, acc[tt]);
        }
        finish(acc, t, FalseT{});
    }
}

extern "C" void kernel_launch(void* const* d_in, const int* in_sizes, int n_in,
                              void* d_out, int out_size, void* d_ws, size_t ws_size,
                              hipStream_t stream) {
    const void* pm25  = d_in[0];
    const void* feat  = d_in[1];
    const void* W_in  = d_in[2];
    const void* b_in  = d_in[3];
    const void* W_out = d_in[4];
    const void* b_out = d_in[5];
    const void* W_ih  = d_in[6];
    const void* W_hh  = d_in[7];
    const void* b_ih  = d_in[8];
    const void* b_hh  = d_in[9];
    float* ws = (float*)d_ws;

    detect_dtype<<<dim3(1), dim3(256), 0, stream>>>((const unsigned short*)feat, ws);

    lstm_prep<false><<<dim3(1), dim3(128), 0, stream>>>(
        W_in, b_in, W_out, b_out, W_ih, W_hh, b_ih, b_hh, ws);
    lstm_prep<true><<<dim3(1), dim3(128), 0, stream>>>(
        W_in, b_in, W_out, b_out, W_ih, W_hh, b_ih, b_hh, ws);

    lstm_main<false><<<dim3(BC_/16), dim3(64), 0, stream>>>(pm25, feat, ws, d_out);
    lstm_main<true ><<<dim3(BC_/16), dim3(64), 0, stream>>>(pm25, feat, ws, d_out);
}

// Round 2
// 359.516 us; speedup vs baseline: 1.8814x; 1.0393x over previous
//
#include <hip/hip_runtime.h>
#include <hip/hip_bf16.h>

// Problem constants
#define B_    512
#define HIST_ 8
#define PRED_ 24
#define CITY_ 184
#define FEAT_ 13
#define HID_  32
#define BC_   (B_*CITY_)   // 94208 = 1472 * 64
#define FLAG_OFF 7168

// ws (float) layout (written by prep_all; rows PERMUTED, see below):
//   [0..4095]      Wh2[p*32+k] : W_hh + a0 (x) W_out   (t>=1 path)
//   [4096..6143]   Wf [p*16+f] : W_x[:,1:14], cols 13..15 zeroed
//   [6144..6271]   bg2[p]      : b_g + a0*b_out        (t>=1)
//   [6272..6399]   a0 [p]      : W_x[:,0]              (t==0)
//   [6400..6527]   bg0[p]      : b_g                   (t==0)
//   [6528..6559]   wout[u]     : unit-indexed (NOT permuted)
//   [6560]         bout
//   [7168]         dtype flag: 0.0f = bf16 inputs, 1.0f = fp32 inputs
//
// Row permutation: original gate-row j = 32*gate + u (gate 0..3 = i,f,g,o,
// unit u 0..31) is stored at p = 16*tt + 4*(u>>3) + (psi&3), where
// psi = u&7, tt = 2*gate + (psi>>2).  Consequence: the 16x16 MFMA D-tile
// at lane (rho=lane&15, q=lane>>4) holds rows 16tt+4q+r = gates
// (gate=tt>>1) of units 8q + 4*(tt&1) + r, seq rho -- i.e. each lane owns
// the complete i/f/g/o set for units {8q..8q+7} of its own sequence, which
// is EXACTLY the B-fragment k-slice (k = 8*(lane>>4)+elem) it must supply
// next step.  h never leaves the lane; no LDS at all.

struct TrueT  { static constexpr bool value = true;  };
struct FalseT { static constexpr bool value = false; };

typedef _Float16 v8hf __attribute__((ext_vector_type(8)));
typedef _Float16 v4hf __attribute__((ext_vector_type(4)));
typedef float    v4f  __attribute__((ext_vector_type(4)));

__device__ __forceinline__ float rcp_(float x) { return __builtin_amdgcn_rcpf(x); }
__device__ __forceinline__ float sigf(float x) { return rcp_(1.0f + __expf(-x)); }
__device__ __forceinline__ float tanhf_(float x) {
    float e = __expf(2.0f * x);
    return 1.0f - 2.0f * rcp_(e + 1.0f);   // saturates correctly (rcp(inf)=0)
}

template<bool F32>
__device__ __forceinline__ float ldin(const void* p, long i) {
    if constexpr (F32) return ((const float*)p)[i];
    else               return __bfloat162float(((const __hip_bfloat16*)p)[i]);
}
template<bool F32>
__device__ __forceinline__ void stout(void* p, long i, float v) {
    if constexpr (F32) ((float*)p)[i] = v;
    else               ((__hip_bfloat16*)p)[i] = __float2bfloat16(v);
}

// MFMA wrappers. K16 legacy builtin guarded: the K32 fallback with zero-padded
// element slots is exactly equivalent (A/B share the (lane,elem)->k labeling).
__device__ __forceinline__ v4f mfma_k32(v8hf a, v8hf b, v4f c) {
    return __builtin_amdgcn_mfma_f32_16x16x32_f16(a, b, c, 0, 0, 0);
}
__device__ __forceinline__ v4f mfma_k16(v4hf a, v4hf b, v4f c) {
#if __has_builtin(__builtin_amdgcn_mfma_f32_16x16x16f16)
    return __builtin_amdgcn_mfma_f32_16x16x16f16(a, b, c, 0, 0, 0);
#else
    v8hf a8; v8hf b8;
    #pragma unroll
    for (int j = 0; j < 4; ++j) { a8[j] = a[j]; b8[j] = b[j]; }
    #pragma unroll
    for (int j = 4; j < 8; ++j) { a8[j] = (_Float16)0.f; b8[j] = (_Float16)0.f; }
    return __builtin_amdgcn_mfma_f32_16x16x32_f16(a8, b8, c, 0, 0, 0);
#endif
}

// ---- prep body (templated on dtype), writes permuted rows ----
template<bool F32>
__device__ __forceinline__ void prep_body(const void* W_in, const void* b_in,
                                          const void* W_out, const void* b_out,
                                          const void* W_ih, const void* W_hh,
                                          const void* b_ih, const void* b_hh,
                                          float* ws, int j)
{
    if (j >= 128) return;
    // original gate-row j -> permuted position p
    const int gate = j >> 5;
    const int u    = j & 31;
    const int qb   = u >> 3;
    const int psi  = u & 7;
    const int tt   = 2*gate + (psi >> 2);
    const int p    = 16*tt + 4*qb + (psi & 3);

    float wx[14];
    #pragma unroll
    for (int c = 0; c < 14; ++c) wx[c] = 0.0f;
    float bg = ldin<F32>(b_ih, j) + ldin<F32>(b_hh, j);
    #pragma unroll
    for (int m = 0; m < 32; ++m) {
        float wihm = ldin<F32>(W_ih, j*32 + m);
        #pragma unroll
        for (int c = 0; c < 14; ++c) wx[c] = fmaf(wihm, ldin<F32>(W_in, m*14 + c), wx[c]);
        bg = fmaf(wihm, ldin<F32>(b_in, m), bg);
    }
    float a0 = wx[0];
    #pragma unroll
    for (int k = 0; k < 32; ++k)
        ws[p*32 + k] = ldin<F32>(W_hh, j*32 + k) + a0 * ldin<F32>(W_out, k);
    #pragma unroll
    for (int f = 0; f < 13; ++f) ws[4096 + p*16 + f] = wx[1 + f];
    #pragma unroll
    for (int f = 13; f < 16; ++f) ws[4096 + p*16 + f] = 0.0f;  // pad (never poison)
    float bo = ldin<F32>(b_out, 0);
    ws[6144 + p] = bg + a0 * bo;
    ws[6272 + p] = a0;
    ws[6400 + p] = bg;
    if (j < 32) ws[6528 + j] = ldin<F32>(W_out, j);   // unit-indexed, unpermuted
    if (j == 0) ws[6560] = bo;
}

// ---- fused detect + prep: one launch ----
__global__ void prep_all(const unsigned short* __restrict__ feat_raw,
                         const void* __restrict__ W_in,  const void* __restrict__ b_in,
                         const void* __restrict__ W_out, const void* __restrict__ b_out,
                         const void* __restrict__ W_ih,  const void* __restrict__ W_hh,
                         const void* __restrict__ b_ih,  const void* __restrict__ b_hh,
                         float* __restrict__ ws)
{
    __shared__ int cnt;
    const int tid = threadIdx.x;   // 0..127
    if (tid == 0) cnt = 0;
    __syncthreads();
    int insane = 0;
    for (int i = tid; i < 4096; i += 128) {
        float v = __uint_as_float(((unsigned int)feat_raw[i]) << 16);
        if (!(fabsf(v) < 1e8f)) insane++;
    }
    if (insane) atomicAdd(&cnt, insane);
    __syncthreads();
    const bool f32 = (cnt > 8);
    if (tid == 0) ws[FLAG_OFF] = f32 ? 1.0f : 0.0f;
    if (f32) prep_body<true >(W_in,b_in,W_out,b_out,W_ih,W_hh,b_ih,b_hh,ws,tid);
    else     prep_body<false>(W_in,b_in,W_out,b_out,W_ih,W_hh,b_ih,b_hh,ws,tid);
}

// ---- main LSTM body: zero LDS, h recirculates in-register ----
template<bool F32>
__device__ __forceinline__ void lstm_body(const void* __restrict__ pm25,
                                          const void* __restrict__ feat,
                                          const float* __restrict__ ws,
                                          void* __restrict__ out)
{
    const int lane = threadIdx.x & 63;
    const int rho  = lane & 15;      // seq within wave / A-row / D-col
    const int q    = lane >> 4;      // k-block / D-row-block / unit-block
    const int wv   = threadIdx.x >> 6;
    const int wseq = (blockIdx.x*4 + wv) * 16;
    const int seq  = wseq + rho;
    const int bb   = seq / CITY_;
    const int city = seq - bb*CITY_;

    // ---- weights -> fp16 hi/lo A-fragments (once per wave) ----
    v8hf Whi0[8], Wlo0[8];
    v4hf Whi1[8], Wlo1[8];
    v4f  bias2[8];
    #pragma unroll
    for (int tt = 0; tt < 8; ++tt) {
        const float* wr = ws + (16*tt + rho)*32 + 8*q;
        #pragma unroll
        for (int j = 0; j < 8; ++j) {
            const float w = wr[j];
            const _Float16 h = (_Float16)w;
            Whi0[tt][j] = h;
            Wlo0[tt][j] = (_Float16)(w - (float)h);
        }
        const float* wf = ws + 4096 + (16*tt + rho)*16 + 4*q;
        #pragma unroll
        for (int j = 0; j < 4; ++j) {
            const float w = wf[j];
            const _Float16 h = (_Float16)w;
            Whi1[tt][j] = h;
            Wlo1[tt][j] = (_Float16)(w - (float)h);
        }
        bias2[tt] = *(const v4f*)(ws + 6144 + 16*tt + 4*q);   // C rows 16tt+4q+r
    }
    float wo8[8];
    #pragma unroll
    for (int j = 0; j < 8; ++j) wo8[j] = ws[6528 + 8*q + j]; // wout[unit 8q+j]
    const float bo = ws[6560];
    const long obase = (long)bb*PRED_*CITY_ + city;

    // ---- per-lane direct feature loads (no LDS): elems 4q..4q+3, clamped.
    // Cols 13..15 of Wf are exactly zero, so clamped duplicates contribute 0.
    int eoff[4];
    #pragma unroll
    for (int j = 0; j < 4; ++j) {
        const int e = 4*q + j;
        eoff[j] = (e < FEAT_) ? e : (FEAT_-1);
    }
    long fbase = ((long)(bb*(HIST_+PRED_) + HIST_)*CITY_ + city)*FEAT_;
    float fn[4];
    auto ldfeat = [&]() {            // prefetch one step's 4 elems into regs
        #pragma unroll
        for (int j = 0; j < 4; ++j) fn[j] = ldin<F32>(feat, fbase + eoff[j]);
        fbase += CITY_ * FEAT_;
    };
    v4hf fhi, flo;
    auto convf = [&]() {             // fn (step t raw) -> fp16 hi/lo fragment
        #pragma unroll
        for (int j = 0; j < 4; ++j) {
            const _Float16 fh = (_Float16)fn[j];
            fhi[j] = fh;
            if constexpr (F32) flo[j] = (_Float16)(fn[j] - (float)fh);
        }
    };

    float cst[8];                    // c-state, units 8q+psi, seq rho
    v8hf  xhi, xlo;                  // h hi/lo: next step's B chunk0 (in-lane!)

    auto finishT = [&](v4f (&acc)[8], int t, auto T0flag) {
        constexpr bool T0 = decltype(T0flag)::value;
        // acc[tt][r]: gate tt>>1 of unit 8q + 4*(tt&1) + r.
        // psi = 4*(tt&1)+r: i=acc[tl], f=acc[2+tl], g=acc[4+tl], o=acc[6+tl]
        float h[8];
        #pragma unroll
        for (int psi = 0; psi < 8; ++psi) {
            const int tl = psi >> 2, r = psi & 3;
            const float I = sigf(acc[tl][r]);
            const float G = tanhf_(acc[4+tl][r]);
            const float O = sigf(acc[6+tl][r]);
            float c;
            if constexpr (T0) c = I*G;
            else              c = fmaf(sigf(acc[2+tl][r]), cst[psi], I*G);
            cst[psi] = c;
            h[psi] = O * tanhf_(c);
        }
        #pragma unroll
        for (int psi = 0; psi < 8; ++psi) {   // pack -> next B fragment
            const _Float16 hh = (_Float16)h[psi];
            xhi[psi] = hh;
            xlo[psi] = (_Float16)(h[psi] - (float)hh);
        }
        float y = 0.0f;                       // y_t = wout . h + bout
        #pragma unroll
        for (int psi = 0; psi < 8; ++psi) y = fmaf(wo8[psi], h[psi], y);
        y += __shfl_xor(y, 16);
        y += __shfl_xor(y, 32);
        if (q == 0) stout<F32>(out, obase + (long)t*CITY_, y + bo);
    };

    // ---- t = 0 : gates = a0*x0 + bg0 (C-init) + Wf.feat (h0 = 0) ----
    ldfeat();            // t=0 features
    convf();
    ldfeat();            // t=1 features in flight
    {
        const float x0 = ldin<F32>(pm25, (long)(bb*HIST_ + (HIST_-1))*CITY_ + city);
        v4f acc[8];
        #pragma unroll
        for (int tt = 0; tt < 8; ++tt) {
            const v4f bg0 = *(const v4f*)(ws + 6400 + 16*tt + 4*q);
            const v4f a0  = *(const v4f*)(ws + 6272 + 16*tt + 4*q);
            v4f c;
            #pragma unroll
            for (int r = 0; r < 4; ++r) c[r] = fmaf(a0[r], x0, bg0[r]);
            v4f a = mfma_k16(Whi1[tt], fhi, c);
            a = mfma_k16(Wlo1[tt], fhi, a);
            if constexpr (F32) a = mfma_k16(Whi1[tt], flo, a);
            acc[tt] = a;
        }
        finishT(acc, 0, TrueT{});
    }

    // ---- t = 1..23 ----
    #pragma unroll 1
    for (int t = 1; t < PRED_; ++t) {
        convf();                        // features for t (loaded last iter)
        if (t < PRED_-1) ldfeat();      // prefetch t+1
        v4f acc[8];
        #pragma unroll
        for (int tt = 0; tt < 8; ++tt) {
            v4f a = mfma_k32(Whi0[tt], xhi, bias2[tt]);
            a = mfma_k32(Wlo0[tt], xhi, a);
            a = mfma_k32(Whi0[tt], xlo, a);
            a = mfma_k16(Whi1[tt], fhi, a);
            a = mfma_k16(Wlo1[tt], fhi, a);
            if constexpr (F32) a = mfma_k16(Whi1[tt], flo, a);
            acc[tt] = a;
        }
        finishT(acc, t, FalseT{});
    }
}

__global__ __launch_bounds__(256, 2) void lstm_main(
    const void* __restrict__ pm25,   // (512, 8, 184, 1)
    const void* __restrict__ feat,   // (512, 32, 184, 13)
    const float* __restrict__ ws,
    void* __restrict__ out)          // (512, 24, 184, 1)
{
    const bool f32 = (ws[FLAG_OFF] == 1.0f);   // wave-uniform runtime branch
    if (f32) lstm_body<true >(pm25, feat, ws, out);
    else     lstm_body<false>(pm25, feat, ws, out);
}

extern "C" void kernel_launch(void* const* d_in, const int* in_sizes, int n_in,
                              void* d_out, int out_size, void* d_ws, size_t ws_size,
                              hipStream_t stream) {
    const void* pm25  = d_in[0];
    const void* feat  = d_in[1];
    const void* W_in  = d_in[2];
    const void* b_in  = d_in[3];
    const void* W_out = d_in[4];
    const void* b_out = d_in[5];
    const void* W_ih  = d_in[6];
    const void* W_hh  = d_in[7];
    const void* b_ih  = d_in[8];
    const void* b_hh  = d_in[9];
    float* ws = (float*)d_ws;

    prep_all<<<dim3(1), dim3(128), 0, stream>>>(
        (const unsigned short*)feat, W_in, b_in, W_out, b_out,
        W_ih, W_hh, b_ih, b_hh, ws);

    lstm_main<<<dim3(BC_/64), dim3(256), 0, stream>>>(pm25, feat, ws, d_out);
}